// Round 1
// 289.028 us; speedup vs baseline: 1.0073x; 1.0073x over previous
//
#include <hip/hip_runtime.h>
#include <math.h>

// Problem constants (from reference)
#define Bdim   32768
#define Ndim   64
#define KT     10                 // K0(8) + SHARED(2)
#define BN     (Bdim * Ndim)
#define DELTA  1e-06f
#define LOG1MD (-1.0000005000001665e-06f)   // log(1 - 1e-6)

#define PTS    256                // points per block (= blockDim.x)

// No LDS staging: each point's 24 params live at dsp + idx*24 floats.
// idx*96 bytes is 16B-aligned, so 6 aligned dwordx4 loads per thread cover
// them. Per-instruction coalescing is worse (stride 96B across lanes), but
// every fetched line is fully consumed within the wave and block boundaries
// land exactly on 128B lines (256*96B = 192 lines), so HBM traffic is
// identical to the staged version. L1 has ~10x line-throughput headroom over
// the HBM demand rate, so this cannot become the new bottleneck. Dropping
// LDS removes the barrier and lifts the occupancy cap (was 5 blocks/CU).
__global__ __launch_bounds__(256) void sigmoid_flow_kernel(
    const float* __restrict__ x,
    const float* __restrict__ logdet,
    const float* __restrict__ dsp,     // (B, N, 3, 8): 24 contiguous floats per point
    const float* __restrict__ shp,     // (1, N, 3, 2): 384 floats, L1/L2-resident
    float* __restrict__ out)           // [0,BN): xnew ; [BN,2BN): logdet_out
{
    const int t   = threadIdx.x;
    const int idx = blockIdx.x * PTS + t;

    // Issue all global loads up front so they overlap.
    const float4* g = (const float4*)dsp + (size_t)idx * 6;
    const float4 v0 = g[0];            // a[0..3]
    const float4 v1 = g[1];            // a[4..7]
    const float4 v2 = g[2];            // b[0..3]
    const float4 v3 = g[3];            // b[4..7]
    const float4 v4 = g[4];            // w[0..3]
    const float4 v5 = g[5];            // w[4..7]

    const float xv = x[idx];
    const float ld = logdet[idx];

    // shared tail: 6 floats per n at shp + n*6, layout [a0,a1,b0,b1,w0,w1].
    // n = idx % 64 == t % 64. 24B offset -> float2 (8B) aligned.
    const float2* sh2 = (const float2*)shp + (size_t)(t & 63) * 3;
    const float2 sa = sh2[0];
    const float2 sb = sh2[1];
    const float2 sw = sh2[2];

    float ap[KT], bp[KT], wl[KT];
    ap[0] = v0.x; ap[1] = v0.y; ap[2] = v0.z; ap[3] = v0.w;
    ap[4] = v1.x; ap[5] = v1.y; ap[6] = v1.z; ap[7] = v1.w;
    bp[0] = v2.x; bp[1] = v2.y; bp[2] = v2.z; bp[3] = v2.w;
    bp[4] = v3.x; bp[5] = v3.y; bp[6] = v3.z; bp[7] = v3.w;
    wl[0] = v4.x; wl[1] = v4.y; wl[2] = v4.z; wl[3] = v4.w;
    wl[4] = v5.x; wl[5] = v5.y; wl[6] = v5.z; wl[7] = v5.w;
    ap[8] = sa.x; ap[9] = sa.y;
    bp[8] = sb.x; bp[9] = sb.y;
    wl[8] = sw.x; wl[9] = sw.y;

    // Linear-domain fused pass. Per k:
    //   a   = softplus(ap)+1e-3
    //   pre = a*x + b
    //   sig = sigmoid(pre);  dsig = sig*(1-sig) = e/(1+e)^2,  e = exp(-|pre|)
    //   x_pre += wexp*sig ;  S += wexp*a*dsig
    // logsumexp(logj) = log(S/wsum) - 0.002   (the two +1e-3 of _logsigmoid)
    float wsum = 0.0f, x_pre = 0.0f, S = 0.0f;
    #pragma unroll
    for (int k = 0; k < KT; ++k) {
        float we = __expf(wl[k]);                       // logits ~N(0,1): no max-shift needed
        wsum += we;
        float t0 = ap[k];
        float e1 = __expf(-fabsf(t0));
        float a  = fmaxf(t0, 0.0f) + __logf(1.0f + e1) + 0.001f;   // _softplus
        float pre = fmaf(a, xv, bp[k]);
        float e  = __expf(-fabsf(pre));
        float r  = __builtin_amdgcn_rcpf(1.0f + e);
        float sig = ((pre >= 0.0f) ? 1.0f : e) * r;
        x_pre = fmaf(we, sig, x_pre);
        S = fmaf(we * a, (e * r) * r, S);
    }
    float invw = __builtin_amdgcn_rcpf(wsum);
    x_pre *= invw;
    float lse = __logf(S * invw) - 0.002f;

    // clip + logit, with fma forms to avoid cancellation near 0/1
    float xc   = fmaf(x_pre, 1.0f - DELTA, 0.5f * DELTA);
    float omxc = fmaf(-(1.0f - DELTA), x_pre, 1.0f - 0.5f * DELTA);  // 1 - xc
    float lxc  = __logf(xc);
    float l1xc = __logf(omxc);

    out[idx]      = lxc - l1xc;                          // xnew
    out[BN + idx] = ld + lse + LOG1MD - (lxc + l1xc);    // logdet_out
}

extern "C" void kernel_launch(void* const* d_in, const int* in_sizes, int n_in,
                              void* d_out, int out_size, void* d_ws, size_t ws_size,
                              hipStream_t stream) {
    const float* x   = (const float*)d_in[0];
    const float* ld  = (const float*)d_in[1];
    const float* dsp = (const float*)d_in[2];
    const float* shp = (const float*)d_in[3];
    float* out = (float*)d_out;

    const int grid = BN / PTS;   // 8192 blocks, exact
    sigmoid_flow_kernel<<<grid, PTS, 0, stream>>>(x, ld, dsp, shp, out);
}